// Round 2
// baseline (358.310 us; speedup 1.0000x reference)
//
#include <hip/hip_runtime.h>
#include <hip/hip_bf16.h>

#define M_DIM 8192
#define K_DIM 2048
#define N_DIM 4096
#define NGROUP 32
#define EPSV 1e-5f
#define NKT (K_DIM / 64)

typedef __bf16 bf16x8 __attribute__((ext_vector_type(8)));
typedef float floatx4 __attribute__((ext_vector_type(4)));

__device__ __forceinline__ void g2lds16(const void* g, void* l) {
    __builtin_amdgcn_global_load_lds(
        (__attribute__((address_space(1))) void*)(uintptr_t)g,
        (__attribute__((address_space(3))) void*)(uint32_t)(uintptr_t)l,
        16, 0, 0);
}

// ---------------- kernel 1: fp32 -> bf16 cast of x and W ----------------
__global__ __launch_bounds__(256) void convert_bf16(
    const float* __restrict__ x, const float* __restrict__ w,
    __bf16* __restrict__ xb, __bf16* __restrict__ wb)
{
    const size_t nx = (size_t)M_DIM * K_DIM / 8;
    const size_t nw = (size_t)N_DIM * K_DIM / 8;
    size_t i = (size_t)blockIdx.x * 256 + threadIdx.x;
    const float4* src;
    bf16x8* dst;
    size_t j;
    if (i < nx) { src = (const float4*)x; dst = (bf16x8*)xb; j = i; }
    else if (i < nx + nw) { src = (const float4*)w; dst = (bf16x8*)wb; j = i - nx; }
    else return;
    float4 a = src[j * 2];
    float4 b = src[j * 2 + 1];
    bf16x8 o = { (__bf16)a.x, (__bf16)a.y, (__bf16)a.z, (__bf16)a.w,
                 (__bf16)b.x, (__bf16)b.y, (__bf16)b.z, (__bf16)b.w };
    dst[j] = o;
}

// ---- kernel 2: 256x256 8-phase bf16 MFMA GEMM fused with GroupNorm + group-min ----
// R6 = R5 resubmission (round 1 died to container-level infra failure; kernel
// re-audited: uniform barriers, satisfiable waitcnts, both double-buffer
// hazard directions barrier-ordered — no deadlock path; 128 KiB static LDS is
// proven on gfx950 by the m201 template).
// Structure: T3+T4+T5. BM=BN=256, BK=64, 512 thr = 8 waves (2M x 4N).
// Per-wave output 128x64 (acc[8][4] 16x16 frags). LDS 128 KiB: double-buffered
// 256x64 bf16 tiles for A and B, chunk-XOR swizzle (proven conflict-free)
// applied via pre-swizzled GLOBAL source so global_load_lds dest stays linear.
// Per K-tile: 4 phases {ds_read subtile | 2x global_load_lds prefetch ->
// s_barrier -> lgkmcnt(0) -> setprio(1) 16 MFMA setprio(0) -> s_barrier};
// vmcnt gate ONCE per K-tile at vmcnt(2) — next tile's first 2 loads stay in
// flight across the barrier; never drained to 0 in the main loop (T4).
__global__ __launch_bounds__(512, 2) void gemm_gn_min(
    const __bf16* __restrict__ xb, const __bf16* __restrict__ wb,
    const float* __restrict__ bg, const float* __restrict__ gamma,
    const float* __restrict__ beta, float* __restrict__ gmin)
{
    __shared__ __bf16 lA[2][256 * 64];   // 64 KiB
    __shared__ __bf16 lB[2][256 * 64];   // 64 KiB

    const int t = threadIdx.x;
    const int m0 = blockIdx.x * 256;
    const int n0 = blockIdx.y * 256;
    const int w  = t >> 6;        // wave 0..7
    const int wr = w >> 2;        // 0..1  (row half)
    const int wc = w & 3;         // 0..3  (col quarter, 64 cols each)
    const int l  = t & 63;
    const int quad = l >> 4;
    const int r  = l & 15;
    const int r7 = r & 7;

    // staging: 512 threads cover 64 rows x 8 chunks per round; 4 rounds each
    // for the 256-row A and B tiles. round stride 64 rows keeps (row&7) and
    // hence the swizzle invariant.
    const int rowS = t >> 3;          // 0..63
    const int cS   = t & 7;
    const int cSw  = cS ^ (rowS & 7); // swizzled global chunk
    const __bf16* gA = xb + (size_t)(m0 + rowS) * K_DIM + cSw * 8;
    const __bf16* gB = wb + (size_t)(n0 + rowS) * K_DIM + cSw * 8;
    const int sOff = rowS * 64 + cS * 8;   // linear LDS dest (elements)

    // fragment read bases (swizzled on the read side, same XOR)
    const int aBase = (wr * 128 + r) * 64;
    const int bBase = (wc * 64  + r) * 64;
    const int ck0 = (quad ^ r7) * 8;        // ks=0 chunk offset (elements)
    const int ck1 = ((4 + quad) ^ r7) * 8;  // ks=1

    floatx4 acc[8][4];
    #pragma unroll
    for (int i = 0; i < 8; ++i)
        #pragma unroll
        for (int j = 0; j < 4; ++j)
            acc[i][j] = (floatx4){0.f, 0.f, 0.f, 0.f};

#define SA(BUF, KK, J) g2lds16(gA + (KK) + (size_t)((J) * 64) * K_DIM, \
                               (void*)&lA[BUF][(J) * 4096 + sOff])
#define SB(BUF, KK, J) g2lds16(gB + (KK) + (size_t)((J) * 64) * K_DIM, \
                               (void*)&lB[BUF][(J) * 4096 + sOff])

#define PH_PRE  __builtin_amdgcn_sched_barrier(0);                        \
                __builtin_amdgcn_s_barrier();                             \
                asm volatile("s_waitcnt lgkmcnt(0)" ::: "memory");        \
                __builtin_amdgcn_sched_barrier(0);                        \
                __builtin_amdgcn_s_setprio(1);
#define PH_POST __builtin_amdgcn_s_setprio(0);                            \
                __builtin_amdgcn_sched_barrier(0);                        \
                __builtin_amdgcn_s_barrier();

#define TILE_STEP(C, KT, PF)                                                   \
  do {                                                                         \
    const int kn_ = ((KT) + 1) * 64;                                           \
    if (PF) {                                                                  \
      SA(1 - (C), kn_, 0); SA(1 - (C), kn_, 1);                                \
      asm volatile("s_waitcnt vmcnt(2)" ::: "memory");                         \
    } else {                                                                   \
      (void)kn_;                                                               \
      asm volatile("s_waitcnt vmcnt(0)" ::: "memory");                         \
    }                                                                          \
    __builtin_amdgcn_sched_barrier(0);                                         \
    __builtin_amdgcn_s_barrier();                                              \
    __builtin_amdgcn_sched_barrier(0);                                         \
    bf16x8 af[4][2], b0[2][2], b1[2][2];                                       \
    /* ---- phase 0: read A-half0 (mt 0..3) + B-half0 (nt 0..1) ---- */        \
    _Pragma("unroll")                                                          \
    for (int mt = 0; mt < 4; ++mt) {                                           \
      af[mt][0] = *(const bf16x8*)&lA[C][aBase + mt * 1024 + ck0];             \
      af[mt][1] = *(const bf16x8*)&lA[C][aBase + mt * 1024 + ck1];             \
    }                                                                          \
    _Pragma("unroll")                                                          \
    for (int nt = 0; nt < 2; ++nt) {                                           \
      b0[nt][0] = *(const bf16x8*)&lB[C][bBase + nt * 1024 + ck0];             \
      b0[nt][1] = *(const bf16x8*)&lB[C][bBase + nt * 1024 + ck1];             \
    }                                                                          \
    if (PF) { SA(1 - (C), kn_, 2); SA(1 - (C), kn_, 3); }                      \
    PH_PRE                                                                     \
    _Pragma("unroll")                                                          \
    for (int mt = 0; mt < 4; ++mt)                                             \
      _Pragma("unroll")                                                        \
      for (int nt = 0; nt < 2; ++nt)                                           \
        _Pragma("unroll")                                                      \
        for (int ks = 0; ks < 2; ++ks)                                         \
          acc[mt][nt] = __builtin_amdgcn_mfma_f32_16x16x32_bf16(               \
              af[mt][ks], b0[nt][ks], acc[mt][nt], 0, 0, 0);                   \
    PH_POST                                                                    \
    /* ---- phase 1: read B-half1 (nt 2..3) ---- */                            \
    _Pragma("unroll")                                                          \
    for (int nt = 0; nt < 2; ++nt) {                                           \
      b1[nt][0] = *(const bf16x8*)&lB[C][bBase + (nt + 2) * 1024 + ck0];       \
      b1[nt][1] = *(const bf16x8*)&lB[C][bBase + (nt + 2) * 1024 + ck1];       \
    }                                                                          \
    if (PF) { SB(1 - (C), kn_, 0); SB(1 - (C), kn_, 1); }                      \
    PH_PRE                                                                     \
    _Pragma("unroll")                                                          \
    for (int mt = 0; mt < 4; ++mt)                                             \
      _Pragma("unroll")                                                        \
      for (int nt = 0; nt < 2; ++nt)                                           \
        _Pragma("unroll")                                                      \
        for (int ks = 0; ks < 2; ++ks)                                         \
          acc[mt][nt + 2] = __builtin_amdgcn_mfma_f32_16x16x32_bf16(           \
              af[mt][ks], b1[nt][ks], acc[mt][nt + 2], 0, 0, 0);               \
    PH_POST                                                                    \
    /* ---- phase 2: reload A-half1 (mt 4..7), B-half0 still live ---- */      \
    _Pragma("unroll")                                                          \
    for (int mt = 0; mt < 4; ++mt) {                                           \
      af[mt][0] = *(const bf16x8*)&lA[C][aBase + (mt + 4) * 1024 + ck0];       \
      af[mt][1] = *(const bf16x8*)&lA[C][aBase + (mt + 4) * 1024 + ck1];       \
    }                                                                          \
    if (PF) { SB(1 - (C), kn_, 2); SB(1 - (C), kn_, 3); }                      \
    PH_PRE                                                                     \
    _Pragma("unroll")                                                          \
    for (int mt = 0; mt < 4; ++mt)                                             \
      _Pragma("unroll")                                                        \
      for (int nt = 0; nt < 2; ++nt)                                           \
        _Pragma("unroll")                                                      \
        for (int ks = 0; ks < 2; ++ks)                                         \
          acc[mt + 4][nt] = __builtin_amdgcn_mfma_f32_16x16x32_bf16(           \
              af[mt][ks], b0[nt][ks], acc[mt + 4][nt], 0, 0, 0);               \
    PH_POST                                                                    \
    /* ---- phase 3: A-half1 x B-half1, no reads, no stage ---- */             \
    PH_PRE                                                                     \
    _Pragma("unroll")                                                          \
    for (int mt = 0; mt < 4; ++mt)                                             \
      _Pragma("unroll")                                                        \
      for (int nt = 0; nt < 2; ++nt)                                           \
        _Pragma("unroll")                                                      \
        for (int ks = 0; ks < 2; ++ks)                                         \
          acc[mt + 4][nt + 2] = __builtin_amdgcn_mfma_f32_16x16x32_bf16(       \
              af[mt][ks], b1[nt][ks], acc[mt + 4][nt + 2], 0, 0, 0);           \
    PH_POST                                                                    \
  } while (0)

    // prologue: stage tile 0 into buf 0 (8 loads/thread), no drain
    SA(0, 0, 0); SA(0, 0, 1); SA(0, 0, 2); SA(0, 0, 3);
    SB(0, 0, 0); SB(0, 0, 1); SB(0, 0, 2); SB(0, 0, 3);

    #pragma unroll 1
    for (int kt2 = 0; kt2 < NKT / 2 - 1; ++kt2) {
        TILE_STEP(0, 2 * kt2, true);
        TILE_STEP(1, 2 * kt2 + 1, true);
    }
    TILE_STEP(0, NKT - 2, true);
    TILE_STEP(1, NKT - 1, false);

    // ---- epilogue: + b_gemm, GroupNorm over 128-col groups, group-min ----
    // C/D layout (verified m89/m91): col = lane&15, row = (lane>>4)*4 + reg.
    // Wave covers 64 cols = half a group; partner wave is wc^1. Exchange
    // (sum, sumsq) then per-row mins through LDS scratch (lA is dead).
    float bgv[4], gv[4], bv[4];
    #pragma unroll
    for (int nt = 0; nt < 4; ++nt) {
        int cg = n0 + wc * 64 + nt * 16 + r;
        bgv[nt] = bg[cg];
        gv[nt]  = gamma[cg];
        bv[nt]  = beta[cg];
    }

    float* sc1 = (float*)&lA[0][0];   // [2 wr][128 row][4 wc][2] = 8 KiB
    float* sc2 = sc1 + 2048;          // [2 wr][128 row][4 wc]    = 4 KiB

    // stage 1: per-row partial (sum, sumsq) over this wave's 64 cols
    #pragma unroll
    for (int mt = 0; mt < 8; ++mt) {
        #pragma unroll
        for (int reg = 0; reg < 4; ++reg) {
            int rowH = mt * 16 + quad * 4 + reg;     // 0..127 within wr half
            float s = 0.f, ss = 0.f;
            #pragma unroll
            for (int nt = 0; nt < 4; ++nt) {
                float y = acc[mt][nt][reg] + bgv[nt];
                s += y;
                ss += y * y;
            }
            #pragma unroll
            for (int d = 1; d < 16; d <<= 1) {       // reduce 16 lanes of quad
                s  += __shfl_xor(s,  d, 64);
                ss += __shfl_xor(ss, d, 64);
            }
            if (r == 0) {
                int idx = ((wr * 128 + rowH) * 4 + wc) * 2;
                sc1[idx] = s;
                sc1[idx + 1] = ss;
            }
        }
    }
    __syncthreads();

    // stage 2: full-group stats (own + partner), normalize, per-wave min
    #pragma unroll
    for (int mt = 0; mt < 8; ++mt) {
        #pragma unroll
        for (int reg = 0; reg < 4; ++reg) {
            int rowH = mt * 16 + quad * 4 + reg;
            int ib = (wr * 128 + rowH) * 4;
            float s  = sc1[(ib + wc) * 2]     + sc1[(ib + (wc ^ 1)) * 2];
            float ss = sc1[(ib + wc) * 2 + 1] + sc1[(ib + (wc ^ 1)) * 2 + 1];
            float mean = s * (1.0f / 128.0f);
            float var  = ss * (1.0f / 128.0f) - mean * mean;
            float rstd = rsqrtf(var + EPSV);
            float mn = 1e30f;
            #pragma unroll
            for (int nt = 0; nt < 4; ++nt) {
                float y = acc[mt][nt][reg] + bgv[nt];
                float z = (y - mean) * rstd * gv[nt] + bv[nt];
                mn = fminf(mn, z);
            }
            #pragma unroll
            for (int d = 1; d < 16; d <<= 1)
                mn = fminf(mn, __shfl_xor(mn, d, 64));
            if (r == 0) sc2[ib + wc] = mn;
        }
    }
    __syncthreads();

    // stage 3: combine the two waves of each group, write gmin
    if ((wc & 1) == 0 && r == 0) {
        #pragma unroll
        for (int mt = 0; mt < 8; ++mt) {
            #pragma unroll
            for (int reg = 0; reg < 4; ++reg) {
                int rowH = mt * 16 + quad * 4 + reg;
                int ib = (wr * 128 + rowH) * 4;
                float mn = fminf(sc2[ib + wc], sc2[ib + wc + 1]);
                int R = m0 + wr * 128 + rowH;
                gmin[(size_t)R * NGROUP + blockIdx.y * 2 + (wc >> 1)] = mn;
            }
        }
    }
#undef SA
#undef SB
#undef PH_PRE
#undef PH_POST
#undef TILE_STEP
}

// ---------------- kernel 3: rowmin over groups + broadcast bias ----------------
__global__ __launch_bounds__(256) void finalize(
    const float* __restrict__ gmin, const float* __restrict__ bias,
    float* __restrict__ out)
{
    const int m = blockIdx.x;
    const int t = threadIdx.x;
    float v = gmin[(size_t)m * NGROUP + (t & 31)];
    #pragma unroll
    for (int d = 1; d < 32; d <<= 1)
        v = fminf(v, __shfl_xor(v, d, 64));
    float4* out4 = (float4*)(out + (size_t)m * N_DIM);
    const float4* bias4 = (const float4*)bias;
    for (int i = t; i < N_DIM / 4; i += 256) {
        float4 b = bias4[i];
        out4[i] = make_float4(v + b.x, v + b.y, v + b.z, v + b.w);
    }
}

extern "C" void kernel_launch(void* const* d_in, const int* in_sizes, int n_in,
                              void* d_out, int out_size, void* d_ws, size_t ws_size,
                              hipStream_t stream)
{
    const float* x     = (const float*)d_in[0];
    const float* W     = (const float*)d_in[1];
    const float* bg    = (const float*)d_in[2];
    const float* gamma = (const float*)d_in[3];
    const float* beta  = (const float*)d_in[4];
    const float* bias  = (const float*)d_in[5];
    float* out = (float*)d_out;

    // ws layout: xb (32 MiB bf16) | wb (16 MiB bf16) | gmin (1 MiB fp32)
    __bf16* xb = (__bf16*)d_ws;
    __bf16* wb = xb + (size_t)M_DIM * K_DIM;
    float* gmin = (float*)(wb + (size_t)N_DIM * K_DIM);

    size_t ntot8 = ((size_t)M_DIM * K_DIM + (size_t)N_DIM * K_DIM) / 8;
    int cvt_blocks = (int)((ntot8 + 255) / 256);
    convert_bf16<<<cvt_blocks, 256, 0, stream>>>(x, W, xb, wb);

    dim3 grid(M_DIM / 256, N_DIM / 256);
    gemm_gn_min<<<grid, 512, 0, stream>>>(xb, wb, bg, gamma, beta, gmin);

    finalize<<<M_DIM, 256, 0, stream>>>(gmin, bias, out);
}